// Round 10
// baseline (239.655 us; speedup 1.0000x reference)
//
#include <hip/hip_runtime.h>

// ---------------------------------------------------------------------------
// CausalSelfAttention  B=4 S=2048 H=1024 NH=16 HD=64   (fp32 in, fp32 out)
// R1: attn XOR-swizzled LDS; exp2+fma softmax; setprio.
// R2 LESSON: big launch-bounds reg cuts spill. Small shaves only.
// R3: qkv_gemm sT aliased onto sA/sB -> LDS 32768 B.
// R4 LESSON: occupancy limit is the UNIFIED VGPR+AGPR file.
// R5: qkv_gemm (256,3) 8-reg shave -> 3 blocks/CU. CONFIRMED.
// R6: XCD-aware decode bh=(lid&7)+8*(lid>>7) -> FETCH 153->25 MB. CONFIRMED.
// R7 LESSON: CROSS-TILE K/V-read merge -> mystery scratch traffic (+20 MB).
// R8 LESSON: qt-flip assumed fixed CU<->lid map; dispatch is dynamic. Revert.
// R9: swapped QK^T (S^T layout) + cvt_pk + b64 P-writes: attn 97->79.5 us.
//     CONFIRMED (WRITE stayed 32.8 MB, conflicts only 2.2M).
// R10: attn LDS pipe ~73% busy = top-utilized resource. WITHIN-TILE
//     q-grouping: waves 0,1 -> tile-b, waves 2,3 -> tile-a; each wave owns
//     32 q-rows as 2 groups of 16. K-frag read once -> 2 QK^T MFMAs;
//     V-frag read once -> 2 PV MFMAs. Block LDS reads -44%/iter.
//     Only +16 VGPR (dual score sets in QK^T window); acc total unchanged.
//     p_s -> [4][32*64] (LDS 49152, 3 blocks/CU - traffic binds, not slots).
//     Tripwire: WRITE_SIZE must stay ~33 MB else revert (R7's failure mode).
// MFMA 16x16x32 bf16 layouts (HW-verified):
//   A-frag: A[m=lane&15][k=(lane>>4)*8+j]
//   B-frag: B^T rows, same shape
//   C/D   : col=lane&15, row=(lane>>4)*4+reg   (operand-order independent)
// ---------------------------------------------------------------------------

#define B_   4
#define S_   2048
#define H_   1024
#define NH_  16
#define HD_  64
#define M_   (B_ * S_)

// 0.125 * log2(e)
#define CEXP 0.18033688011112042f

// XOR swizzle: flips 8-short (16B) blocks within a 64-short row
#define SWZ(row, col) ((col) ^ (((row) & 7) << 3))

typedef float          f32x4  __attribute__((ext_vector_type(4)));
typedef short          bf16x8 __attribute__((ext_vector_type(8)));
typedef unsigned short u16x8  __attribute__((ext_vector_type(8)));
typedef unsigned int   u32x2  __attribute__((ext_vector_type(2)));

__device__ __forceinline__ unsigned short f2bf(float f) {
    unsigned int u = __float_as_uint(f);
    u += 0x7fffu + ((u >> 16) & 1u);   // RNE
    return (unsigned short)(u >> 16);
}

// packed f32x2 -> bf16x2 (RNE), gfx950 (no builtin; inline asm per T12)
__device__ __forceinline__ unsigned int cvt_pk_bf16(float lo, float hi) {
    unsigned int r;
    asm("v_cvt_pk_bf16_f32 %0, %1, %2" : "=v"(r) : "v"(lo), "v"(hi));
    return r;
}

// async 16B global->LDS (dest = wave-uniform base + lane*16)
__device__ __forceinline__ void load16_lds(const unsigned short* g, unsigned short* l) {
    __builtin_amdgcn_global_load_lds(
        (const __attribute__((address_space(1))) unsigned int*)g,
        (__attribute__((address_space(3))) unsigned int*)l, 16, 0, 0);
}

// ---------------------------------------------------------------------------
// fused cast, flat grid: blocks [0,4096) hidden | 3x512 weights | 4 mask
__global__ __launch_bounds__(256) void cast_bf16(
    const float* __restrict__ s0, const float* __restrict__ s1,
    const float* __restrict__ s2, const float* __restrict__ s3,
    const float* __restrict__ s4,
    unsigned short* __restrict__ d0, unsigned short* __restrict__ d1,
    unsigned short* __restrict__ d2, unsigned short* __restrict__ d3,
    float* __restrict__ d4) {
    const int bid = blockIdx.x;
    if (bid >= 5632) {   // mask * CEXP -> f32 workspace (4 blocks)
        int i = ((bid - 5632) * 256 + (int)threadIdx.x) * 8;
        if (i + 8 <= B_ * S_) {
            float4 a = *(const float4*)(s4 + i);
            float4 b = *(const float4*)(s4 + i + 4);
            a.x *= CEXP; a.y *= CEXP; a.z *= CEXP; a.w *= CEXP;
            b.x *= CEXP; b.y *= CEXP; b.z *= CEXP; b.w *= CEXP;
            *(float4*)(d4 + i)     = a;
            *(float4*)(d4 + i + 4) = b;
        }
        return;
    }
    const float* src;
    unsigned short* dst;
    int base;
    if (bid < 4096)      { src = s0; dst = d0; base = bid; }
    else if (bid < 4608) { src = s1; dst = d1; base = bid - 4096; }
    else if (bid < 5120) { src = s2; dst = d2; base = bid - 4608; }
    else                 { src = s3; dst = d3; base = bid - 5120; }
    int i = (base * 256 + (int)threadIdx.x) * 8;
    float4 a = *(const float4*)(src + i);
    float4 b = *(const float4*)(src + i + 4);
    u16x8 o;
    o[0] = f2bf(a.x); o[1] = f2bf(a.y); o[2] = f2bf(a.z); o[3] = f2bf(a.w);
    o[4] = f2bf(b.x); o[5] = f2bf(b.y); o[6] = f2bf(b.z); o[7] = f2bf(b.w);
    *(u16x8*)(dst + i) = o;
}

// ---------------------------------------------------------------------------
// QKV GEMM (m97 structure): C[m][n] = sum_k A[m][k]*W[n][k] + bias[n].
// bf16 inputs. 128x128 tile, BK=64, 4 waves, 4x4 accs. Unpadded stride-64
// LDS; staging via global_load_lds dwordx4. z==2 stores V^T [b][h][d][s]
// through an LDS transpose (aliased onto sA/sB; epilogue-only use).
// LDS 32768 B; __launch_bounds__(256,3) caps regs at 168 total -> 3 blocks/CU.
// ---------------------------------------------------------------------------
__global__ __launch_bounds__(256, 3) void qkv_gemm(
    const unsigned short* __restrict__ A,
    const unsigned short* __restrict__ W0, const unsigned short* __restrict__ W1,
    const unsigned short* __restrict__ W2,
    const float* __restrict__ b0, const float* __restrict__ b1,
    const float* __restrict__ b2,
    unsigned short* __restrict__ o0, unsigned short* __restrict__ o1,
    unsigned short* __restrict__ o2) {
    __shared__ unsigned short smem[2 * 128 * 64];      // 32768 B
    unsigned short* sA = smem;                         // [128*64] K-loop
    unsigned short* sB = smem + 128 * 64;              // [128*64] K-loop
    unsigned short* sT = smem;                         // [64*136] epilogue alias (17408 B)

    const int t = threadIdx.x;
    const int w = t >> 6, lane = t & 63, quad = lane >> 4, l15 = lane & 15;
    const int bm = blockIdx.x, bn = blockIdx.y, z = blockIdx.z;

    const unsigned short* W = (z == 0) ? W0 : (z == 1) ? W1 : W2;
    const float*        bia = (z == 0) ? b0 : (z == 1) ? b1 : b2;

    const int wm = (w & 1) * 64, wn = (w >> 1) * 64;

    f32x4 acc[4][4];
#pragma unroll
    for (int i = 0; i < 4; ++i)
#pragma unroll
        for (int j = 0; j < 4; ++j) acc[i][j] = f32x4{0.f, 0.f, 0.f, 0.f};

    const int srow = w * 32 + (lane >> 3);
    const int scol = (lane & 7) * 8;
    const unsigned short* Ag = A + (size_t)(bm * 128 + srow) * H_ + scol;
    const unsigned short* Wg = W + (size_t)(bn * 128 + srow) * H_ + scol;
    unsigned short* lA = &sA[w * 32 * 64];
    unsigned short* lB = &sB[w * 32 * 64];

    for (int kt = 0; kt < 16; ++kt) {
        __syncthreads();
#pragma unroll
        for (int c = 0; c < 4; ++c) {
            load16_lds(Ag + kt * 64 + (size_t)c * 8 * H_, lA + c * 512);
            load16_lds(Wg + kt * 64 + (size_t)c * 8 * H_, lB + c * 512);
        }
        __syncthreads();
#pragma unroll
        for (int kk = 0; kk < 64; kk += 32) {
            bf16x8 af[4], bf[4];
#pragma unroll
            for (int mi = 0; mi < 4; ++mi)
                af[mi] = *(const bf16x8*)&sA[(wm + mi * 16 + l15) * 64 + kk + quad * 8];
#pragma unroll
            for (int ni = 0; ni < 4; ++ni)
                bf[ni] = *(const bf16x8*)&sB[(wn + ni * 16 + l15) * 64 + kk + quad * 8];
#pragma unroll
            for (int mi = 0; mi < 4; ++mi)
#pragma unroll
                for (int ni = 0; ni < 4; ++ni)
                    acc[mi][ni] = __builtin_amdgcn_mfma_f32_16x16x32_bf16(
                        af[mi], bf[ni], acc[mi][ni], 0, 0, 0);
        }
    }

    float bvv[4];
#pragma unroll
    for (int ni = 0; ni < 4; ++ni) bvv[ni] = bia[bn * 128 + wn + ni * 16 + l15];

    if (z != 2) {
        unsigned short* outp = (z == 0) ? o0 : o1;
#pragma unroll
        for (int mi = 0; mi < 4; ++mi)
#pragma unroll
            for (int ni = 0; ni < 4; ++ni)
#pragma unroll
                for (int r = 0; r < 4; ++r) {
                    int m = bm * 128 + wm + mi * 16 + quad * 4 + r;
                    int n = bn * 128 + wn + ni * 16 + l15;
                    outp[(size_t)m * H_ + n] = f2bf(acc[mi][ni][r] + bvv[ni]);
                }
    } else {
        // V^T via LDS transpose: half = n-range 64 (waves 0,1 own half 0).
        // sT aliases sA/sB -> must drain K-loop LDS reads first.
        __syncthreads();
        const int halfw = w >> 1;
        const int bb = bm >> 4;                 // batch of this row-block
        const int s0 = (bm * 128) & 2047;       // seq offset of this row-block
        for (int half = 0; half < 2; ++half) {
            if (half) __syncthreads();          // half-0 reads done before overwrite
            if (halfw == half) {
#pragma unroll
                for (int mi = 0; mi < 4; ++mi)
#pragma unroll
                    for (int ni = 0; ni < 4; ++ni)
#pragma unroll
                        for (int r = 0; r < 4; ++r) {
                            int nl = ni * 16 + l15;
                            int m  = wm + mi * 16 + quad * 4 + r;
                            sT[nl * 136 + m] = f2bf(acc[mi][ni][r] + bvv[ni]);
                        }
            }
            __syncthreads();
            {   // coalesced store: thread t -> row n=t/4, 32 s-elems
                int nl = t >> 2, mc = (t & 3) * 32;
                int ng = bn * 128 + half * 64 + nl;
                int hh = ng >> 6, d = ng & 63;
                size_t base = ((size_t)((bb * NH_ + hh) * HD_ + d)) * S_ + s0 + mc;
#pragma unroll
                for (int i = 0; i < 4; ++i)
                    *(u16x8*)(o2 + base + i * 8) = *(const u16x8*)&sT[nl * 136 + mc + i * 8];
            }
        }
    }
}

// ---------------------------------------------------------------------------
// Flash attention R10: waves 0,1 -> tile-b (qb), waves 2,3 -> tile-a (qa);
// each wave owns 32 q-rows as 2 groups of 16. Shared K-frag reads (1 read ->
// 2 QK^T MFMAs) and shared V-frag reads (1 read -> 2 PV MFMAs): block LDS
// reads -44%/iter. Swapped QK^T (S^T layout), cvt_pk P-pack, b64 P-writes
// into per-wave per-group p_s regions. Single barrier per kt, double-
// buffered K/V, XOR-swizzled stride-64. LDS 49152 B.
// Flat grid 1024, R6 decode: bh=(lid&7)+8*(lid>>7), qt=(lid>>3)&15.
// ---------------------------------------------------------------------------
__global__ __launch_bounds__(256, 3) void attn(
    const unsigned short* __restrict__ qg, const unsigned short* __restrict__ kg,
    const unsigned short* __restrict__ vtg, const float* __restrict__ mcg,
    float* __restrict__ outg) {
    __shared__ unsigned short k_s[2][64 * 64];
    __shared__ unsigned short v_s[2][64 * 64];
    __shared__ unsigned short p_s[4][32 * 64];   // per wave: 2 groups x 16q x 64s

    const int t = threadIdx.x;
    const int w = t >> 6, lane = t & 63, quad = lane >> 4, l15 = lane & 15;
    const int lid = blockIdx.x;
    const int bh = (lid & 7) + ((lid >> 7) << 3);   // XCD-grouped head-batch
    const int qt = (lid >> 3) & 15;                 // q-pair index (R6 decode)
    const int b = bh >> 4, h = bh & 15;
    const int qa = qt, qb = 31 - qt;

    const bool tile_a = (w >= 2);        // wave-uniform tile assignment
    const int sub = w & 1;               // 32-row half within the tile
    const int qtile = tile_a ? qa : qb;
    const int qbase = qtile * 64 + sub * 32;

    const int rs_ = t >> 2;             // staging row 0..63
    const int cs_ = (t & 3) * 16;       // staging col
    const int sc0 = rs_ * 64 + SWZ(rs_, cs_);      // swizzled staging offsets
    const int sc1 = rs_ * 64 + SWZ(rs_, cs_ + 8);

    const unsigned short* kbase = kg + ((size_t)b * S_ + rs_) * H_ + h * HD_ + cs_;
    const unsigned short* vbase = vtg + ((size_t)bh * HD_ + rs_) * S_ + cs_;
    const float* mrow = mcg + b * S_ + quad * 4;   // + kt*64 + jt*16 (float4)

    // Q A-frags for the wave's 2 groups (B-operand of swapped QK^T)
    bf16x8 aq0[2], aq1[2];
    {
        const unsigned short* qp0 =
            qg + ((size_t)(b * S_ + qbase + l15)) * H_ + h * HD_ + quad * 8;
        aq0[0] = *(const bf16x8*)qp0;
        aq0[1] = *(const bf16x8*)(qp0 + 32);
        const unsigned short* qp1 = qp0 + (size_t)16 * H_;
        aq1[0] = *(const bf16x8*)qp1;
        aq1[1] = *(const bf16x8*)(qp1 + 32);
    }

    // prefetch tile 0 into regs
    u16x8 pk0 = *(const u16x8*)kbase, pk1 = *(const u16x8*)(kbase + 8);
    u16x8 pv0 = *(const u16x8*)vbase, pv1 = *(const u16x8*)(vbase + 8);

    f32x4 o0[4], o1[4];
    float ls0 = 0.f, ls1 = 0.f;         // scalar row-sum partials (row q = l15)
#pragma unroll
    for (int dt = 0; dt < 4; ++dt) {
        o0[dt] = f32x4{0.f, 0.f, 0.f, 0.f};
        o1[dt] = f32x4{0.f, 0.f, 0.f, 0.f};
    }

    const int qcol0 = qbase + l15;       // causal col, group 0 (swapped layout)
    const int qcol1 = qbase + 16 + l15;  // group 1

    for (int kt = 0; kt <= qb; ++kt) {
        const int cur = kt & 1;
        // store regs (tile kt) -> buf[cur], swizzled
        *(u16x8*)&k_s[cur][sc0] = pk0;
        *(u16x8*)&k_s[cur][sc1] = pk1;
        *(u16x8*)&v_s[cur][sc0] = pv0;
        *(u16x8*)&v_s[cur][sc1] = pv1;
        // prefetch tile kt+1 -> regs (consumed at next iter's store)
        if (kt < qb) {
            const unsigned short* kp = kbase + (size_t)(kt + 1) * 64 * H_;
            pk0 = *(const u16x8*)kp; pk1 = *(const u16x8*)(kp + 8);
            const unsigned short* vp = vbase + (kt + 1) * 64;
            pv0 = *(const u16x8*)vp; pv1 = *(const u16x8*)(vp + 8);
        }
        __syncthreads();   // buf[cur] visible to all; prev iter compute done

        // wave-uniform activity: tile-b waves always, tile-a waves kt<=qa
        if (!tile_a || kt <= qa) {
            // mask (prescaled by CEXP): mcv[jt][r] at s = kt*64+jt*16+quad*4+r
            float4 mcv[4];
#pragma unroll
            for (int jt = 0; jt < 4; ++jt)
                mcv[jt] = *(const float4*)(mrow + kt * 64 + jt * 16);

            // ===== QK^T, shared K-frags: 1 read -> 2 MFMAs =====
            f32x4 s0[4], s1[4];
#pragma unroll
            for (int jt = 0; jt < 4; ++jt) {
                s0[jt] = f32x4{0.f, 0.f, 0.f, 0.f};
                s1[jt] = f32x4{0.f, 0.f, 0.f, 0.f};
            }
            __builtin_amdgcn_s_setprio(1);
#pragma unroll
            for (int c = 0; c < 2; ++c)
#pragma unroll
                for (int jt = 0; jt < 4; ++jt) {
                    int row = jt * 16 + l15;
                    bf16x8 bk = *(const bf16x8*)&k_s[cur][row * 64 + SWZ(row, c * 32 + quad * 8)];
                    s0[jt] = __builtin_amdgcn_mfma_f32_16x16x32_bf16(bk, aq0[c], s0[jt], 0, 0, 0);
                    s1[jt] = __builtin_amdgcn_mfma_f32_16x16x32_bf16(bk, aq1[c], s1[jt], 0, 0, 0);
                }
            __builtin_amdgcn_s_setprio(0);

            const bool diag = (kt == qtile);
            // ===== softmax group 0 -> p_s[w][0..1023] =====
#pragma unroll
            for (int jt = 0; jt < 4; ++jt) {
                const int sb0 = kt * 64 + jt * 16 + quad * 4;
                float p0 = __builtin_amdgcn_exp2f(__builtin_fmaf(s0[jt][0], CEXP, mcv[jt].x));
                float p1 = __builtin_amdgcn_exp2f(__builtin_fmaf(s0[jt][1], CEXP, mcv[jt].y));
                float p2 = __builtin_amdgcn_exp2f(__builtin_fmaf(s0[jt][2], CEXP, mcv[jt].z));
                float p3 = __builtin_amdgcn_exp2f(__builtin_fmaf(s0[jt][3], CEXP, mcv[jt].w));
                if (diag) {
                    if (sb0 + 0 > qcol0) p0 = 0.f;
                    if (sb0 + 1 > qcol0) p1 = 0.f;
                    if (sb0 + 2 > qcol0) p2 = 0.f;
                    if (sb0 + 3 > qcol0) p3 = 0.f;
                }
                ls0 += (p0 + p1) + (p2 + p3);
                u32x2 pw;
                pw[0] = cvt_pk_bf16(p0, p1);
                pw[1] = cvt_pk_bf16(p2, p3);
                *(u32x2*)&p_s[w][l15 * 64 + SWZ(l15, jt * 16 + quad * 4)] = pw;
            }
            // ===== softmax group 1 -> p_s[w][1024..2047] =====
#pragma unroll
            for (int jt = 0; jt < 4; ++jt) {
                const int sb0 = kt * 64 + jt * 16 + quad * 4;
                float p0 = __builtin_amdgcn_exp2f(__builtin_fmaf(s1[jt][0], CEXP, mcv[jt].x));
                float p1 = __builtin_amdgcn_exp2f(__builtin_fmaf(s1[jt][1], CEXP, mcv[jt].y));
                float p2 = __builtin_amdgcn_exp2f(__builtin_fmaf(s1[jt][2], CEXP, mcv[jt].z));
                float p3 = __builtin_amdgcn_exp2f(__builtin_fmaf(s1[jt][3], CEXP, mcv[jt].w));
                if (diag) {
                    if (sb0 + 0 > qcol1) p0 = 0.f;
                    if (sb0 + 1 > qcol1) p1 = 0.f;
                    if (sb0 + 2 > qcol1) p2 = 0.f;
                    if (sb0 + 3 > qcol1) p3 = 0.f;
                }
                ls1 += (p0 + p1) + (p2 + p3);
                u32x2 pw;
                pw[0] = cvt_pk_bf16(p0, p1);
                pw[1] = cvt_pk_bf16(p2, p3);
                *(u32x2*)&p_s[w][1024 + l15 * 64 + SWZ(l15, jt * 16 + quad * 4)] = pw;
            }

            // ===== PV, shared V-frags: 1 read -> 2 MFMAs =====
            __builtin_amdgcn_s_setprio(1);
#pragma unroll
            for (int c = 0; c < 2; ++c) {
                bf16x8 ap0 = *(const bf16x8*)&p_s[w][l15 * 64 + SWZ(l15, c * 32 + quad * 8)];
                bf16x8 ap1 = *(const bf16x8*)&p_s[w][1024 + l15 * 64 + SWZ(l15, c * 32 + quad * 8)];
#pragma unroll
                for (int dt = 0; dt < 4; ++dt) {
                    int row = dt * 16 + l15;
                    bf16x8 bv = *(const bf16x8*)&v_s[cur][row * 64 + SWZ(row, c * 32 + quad * 8)];
                    o0[dt] = __builtin_amdgcn_mfma_f32_16x16x32_bf16(ap0, bv, o0[dt], 0, 0, 0);
                    o1[dt] = __builtin_amdgcn_mfma_f32_16x16x32_bf16(ap1, bv, o1[dt], 0, 0, 0);
                }
            }
            __builtin_amdgcn_s_setprio(0);
        }
    }

    // ---- epilogue: complete row sums (rows live at q = l15 per group),
    // redistribute to O-accumulator rows (quad*4+r), normalize, store ----
    float sA = ls0, sB = ls1;
    sA += __shfl_xor(sA, 16); sA += __shfl_xor(sA, 32);
    sB += __shfl_xor(sB, 16); sB += __shfl_xor(sB, 32);
    float r0[4], r1[4];
#pragma unroll
    for (int r = 0; r < 4; ++r) {
        int src = (quad << 4) | (quad * 4 + r);   // lane with l15 = quad*4+r
        r0[r] = 1.0f / __shfl(sA, src);
        r1[r] = 1.0f / __shfl(sB, src);
    }
#pragma unroll
    for (int dt = 0; dt < 4; ++dt)
#pragma unroll
        for (int r = 0; r < 4; ++r) {
            int col = h * HD_ + dt * 16 + l15;
            outg[(size_t)(b * S_ + qbase + quad * 4 + r) * H_ + col]      = o0[dt][r] * r0[r];
            outg[(size_t)(b * S_ + qbase + 16 + quad * 4 + r) * H_ + col] = o1[dt][r] * r1[r];
        }
}

// ---------------------------------------------------------------------------
extern "C" void kernel_launch(void* const* d_in, const int* in_sizes, int n_in,
                              void* d_out, int out_size, void* d_ws, size_t ws_size,
                              hipStream_t stream) {
    const float* hs   = (const float*)d_in[0];
    const float* mask = (const float*)d_in[1];
    const float* Wq   = (const float*)d_in[2];
    const float* bq   = (const float*)d_in[3];
    const float* Wk   = (const float*)d_in[4];
    const float* bk   = (const float*)d_in[5];
    const float* Wv   = (const float*)d_in[6];
    const float* bv   = (const float*)d_in[7];
    float* out = (float*)d_out;

    // ws carve (bf16 elems): hsb 8M | wq,wk,wv 1M | q 8M | k 8M | vT 8M | mc 8K f32
    unsigned short* hsb = (unsigned short*)d_ws;
    unsigned short* wqb = hsb + (size_t)M_ * H_;
    unsigned short* wkb = wqb + (size_t)H_ * H_;
    unsigned short* wvb = wkb + (size_t)H_ * H_;
    unsigned short* qb  = wvb + (size_t)H_ * H_;
    unsigned short* kb  = qb  + (size_t)M_ * H_;
    unsigned short* vtb = kb  + (size_t)M_ * H_;
    float*          mcw = (float*)(vtb + (size_t)M_ * H_);

    cast_bf16<<<dim3(5636), 256, 0, stream>>>(
        hs, Wq, Wk, Wv, mask, hsb, wqb, wkb, wvb, mcw);

    qkv_gemm<<<dim3(M_ / 128, H_ / 128, 3), 256, 0, stream>>>(
        hsb, wqb, wkb, wvb, bq, bk, bv, qb, kb, vtb);

    attn<<<dim3(1024), 256, 0, stream>>>(qb, kb, vtb, mcw, out);
}

// Round 12
// 224.631 us; speedup vs baseline: 1.0669x; 1.0669x over previous
//
#include <hip/hip_runtime.h>

// ---------------------------------------------------------------------------
// CausalSelfAttention  B=4 S=2048 H=1024 NH=16 HD=64   (fp32 in, fp32 out)
// R1: attn XOR-swizzled LDS; exp2+fma softmax; setprio.
// R2 LESSON: big launch-bounds reg cuts spill. Small shaves only.
// R3: qkv_gemm sT aliased onto sA/sB -> LDS 32768 B.
// R4 LESSON: occupancy limit is the UNIFIED VGPR+AGPR file.
// R5: qkv_gemm (256,3) 8-reg shave -> 3 blocks/CU. CONFIRMED.
// R6: XCD-aware decode -> FETCH 153->25 MB. CONFIRMED.
// R7 LESSON: cross-tile merge -> scratch spill. Reverted.
// R8 LESSON: qt-flip assumed fixed CU<->lid map; dispatch is dynamic. Revert.
// R9: swapped QK^T (S^T layout) + cvt_pk + b64 P-writes: attn 97->79.5 us.
// R10 LESSON: wave-split tiles broke per-wave balance (makespan 2x). Revert.
// R11 LESSON: store-ahead single-barrier staging FAILED correctness
//     (absmax 0.27, race unexplained). Sync-structure edits are one-shot
//     unverifiable here -> REVERTED to R9's proven store->barrier->compute.
// R12: UNFUSE the q-pair (deletion-only change from R9): 2048 blocks, one
//     q-tile each (kt=0..qt). Same total compute; staging x1.35 (LDS BW is
//     not binding per R10). Occupancy was ~20% vs 50% cap with no saturated
//     pipe -> TLP-starved; 2x blocks at half duration pack better.
//     Decode: bh=(lid&7)+8*(lid>>8) keeps 8 bh/XCD (both dispatch models);
//     qt=31-((lid>>3)&31) dispatches longest blocks first (LPT tail).
// MFMA 16x16x32 bf16 layouts (HW-verified):
//   A-frag: A[m=lane&15][k=(lane>>4)*8+j]
//   B-frag: B^T rows, same shape
//   C/D   : col=lane&15, row=(lane>>4)*4+reg   (operand-order independent)
// ---------------------------------------------------------------------------

#define B_   4
#define S_   2048
#define H_   1024
#define NH_  16
#define HD_  64
#define M_   (B_ * S_)

// 0.125 * log2(e)
#define CEXP 0.18033688011112042f

// XOR swizzle: flips 8-short (16B) blocks within a 64-short row
#define SWZ(row, col) ((col) ^ (((row) & 7) << 3))

typedef float          f32x4  __attribute__((ext_vector_type(4)));
typedef short          bf16x8 __attribute__((ext_vector_type(8)));
typedef unsigned short u16x8  __attribute__((ext_vector_type(8)));
typedef unsigned int   u32x2  __attribute__((ext_vector_type(2)));

__device__ __forceinline__ unsigned short f2bf(float f) {
    unsigned int u = __float_as_uint(f);
    u += 0x7fffu + ((u >> 16) & 1u);   // RNE
    return (unsigned short)(u >> 16);
}

// packed f32x2 -> bf16x2 (RNE), gfx950 (no builtin; inline asm per T12)
__device__ __forceinline__ unsigned int cvt_pk_bf16(float lo, float hi) {
    unsigned int r;
    asm("v_cvt_pk_bf16_f32 %0, %1, %2" : "=v"(r) : "v"(lo), "v"(hi));
    return r;
}

// async 16B global->LDS (dest = wave-uniform base + lane*16)
__device__ __forceinline__ void load16_lds(const unsigned short* g, unsigned short* l) {
    __builtin_amdgcn_global_load_lds(
        (const __attribute__((address_space(1))) unsigned int*)g,
        (__attribute__((address_space(3))) unsigned int*)l, 16, 0, 0);
}

// ---------------------------------------------------------------------------
// fused cast, flat grid: blocks [0,4096) hidden | 3x512 weights | 4 mask
__global__ __launch_bounds__(256) void cast_bf16(
    const float* __restrict__ s0, const float* __restrict__ s1,
    const float* __restrict__ s2, const float* __restrict__ s3,
    const float* __restrict__ s4,
    unsigned short* __restrict__ d0, unsigned short* __restrict__ d1,
    unsigned short* __restrict__ d2, unsigned short* __restrict__ d3,
    float* __restrict__ d4) {
    const int bid = blockIdx.x;
    if (bid >= 5632) {   // mask * CEXP -> f32 workspace (4 blocks)
        int i = ((bid - 5632) * 256 + (int)threadIdx.x) * 8;
        if (i + 8 <= B_ * S_) {
            float4 a = *(const float4*)(s4 + i);
            float4 b = *(const float4*)(s4 + i + 4);
            a.x *= CEXP; a.y *= CEXP; a.z *= CEXP; a.w *= CEXP;
            b.x *= CEXP; b.y *= CEXP; b.z *= CEXP; b.w *= CEXP;
            *(float4*)(d4 + i)     = a;
            *(float4*)(d4 + i + 4) = b;
        }
        return;
    }
    const float* src;
    unsigned short* dst;
    int base;
    if (bid < 4096)      { src = s0; dst = d0; base = bid; }
    else if (bid < 4608) { src = s1; dst = d1; base = bid - 4096; }
    else if (bid < 5120) { src = s2; dst = d2; base = bid - 4608; }
    else                 { src = s3; dst = d3; base = bid - 5120; }
    int i = (base * 256 + (int)threadIdx.x) * 8;
    float4 a = *(const float4*)(src + i);
    float4 b = *(const float4*)(src + i + 4);
    u16x8 o;
    o[0] = f2bf(a.x); o[1] = f2bf(a.y); o[2] = f2bf(a.z); o[3] = f2bf(a.w);
    o[4] = f2bf(b.x); o[5] = f2bf(b.y); o[6] = f2bf(b.z); o[7] = f2bf(b.w);
    *(u16x8*)(dst + i) = o;
}

// ---------------------------------------------------------------------------
// QKV GEMM (m97 structure): C[m][n] = sum_k A[m][k]*W[n][k] + bias[n].
// bf16 inputs. 128x128 tile, BK=64, 4 waves, 4x4 accs. Unpadded stride-64
// LDS; staging via global_load_lds dwordx4. z==2 stores V^T [b][h][d][s]
// through an LDS transpose (aliased onto sA/sB; epilogue-only use).
// LDS 32768 B; __launch_bounds__(256,3) caps regs at 168 total -> 3 blocks/CU.
// ---------------------------------------------------------------------------
__global__ __launch_bounds__(256, 3) void qkv_gemm(
    const unsigned short* __restrict__ A,
    const unsigned short* __restrict__ W0, const unsigned short* __restrict__ W1,
    const unsigned short* __restrict__ W2,
    const float* __restrict__ b0, const float* __restrict__ b1,
    const float* __restrict__ b2,
    unsigned short* __restrict__ o0, unsigned short* __restrict__ o1,
    unsigned short* __restrict__ o2) {
    __shared__ unsigned short smem[2 * 128 * 64];      // 32768 B
    unsigned short* sA = smem;                         // [128*64] K-loop
    unsigned short* sB = smem + 128 * 64;              // [128*64] K-loop
    unsigned short* sT = smem;                         // [64*136] epilogue alias (17408 B)

    const int t = threadIdx.x;
    const int w = t >> 6, lane = t & 63, quad = lane >> 4, l15 = lane & 15;
    const int bm = blockIdx.x, bn = blockIdx.y, z = blockIdx.z;

    const unsigned short* W = (z == 0) ? W0 : (z == 1) ? W1 : W2;
    const float*        bia = (z == 0) ? b0 : (z == 1) ? b1 : b2;

    const int wm = (w & 1) * 64, wn = (w >> 1) * 64;

    f32x4 acc[4][4];
#pragma unroll
    for (int i = 0; i < 4; ++i)
#pragma unroll
        for (int j = 0; j < 4; ++j) acc[i][j] = f32x4{0.f, 0.f, 0.f, 0.f};

    const int srow = w * 32 + (lane >> 3);
    const int scol = (lane & 7) * 8;
    const unsigned short* Ag = A + (size_t)(bm * 128 + srow) * H_ + scol;
    const unsigned short* Wg = W + (size_t)(bn * 128 + srow) * H_ + scol;
    unsigned short* lA = &sA[w * 32 * 64];
    unsigned short* lB = &sB[w * 32 * 64];

    for (int kt = 0; kt < 16; ++kt) {
        __syncthreads();
#pragma unroll
        for (int c = 0; c < 4; ++c) {
            load16_lds(Ag + kt * 64 + (size_t)c * 8 * H_, lA + c * 512);
            load16_lds(Wg + kt * 64 + (size_t)c * 8 * H_, lB + c * 512);
        }
        __syncthreads();
#pragma unroll
        for (int kk = 0; kk < 64; kk += 32) {
            bf16x8 af[4], bf[4];
#pragma unroll
            for (int mi = 0; mi < 4; ++mi)
                af[mi] = *(const bf16x8*)&sA[(wm + mi * 16 + l15) * 64 + kk + quad * 8];
#pragma unroll
            for (int ni = 0; ni < 4; ++ni)
                bf[ni] = *(const bf16x8*)&sB[(wn + ni * 16 + l15) * 64 + kk + quad * 8];
#pragma unroll
            for (int mi = 0; mi < 4; ++mi)
#pragma unroll
                for (int ni = 0; ni < 4; ++ni)
                    acc[mi][ni] = __builtin_amdgcn_mfma_f32_16x16x32_bf16(
                        af[mi], bf[ni], acc[mi][ni], 0, 0, 0);
        }
    }

    float bvv[4];
#pragma unroll
    for (int ni = 0; ni < 4; ++ni) bvv[ni] = bia[bn * 128 + wn + ni * 16 + l15];

    if (z != 2) {
        unsigned short* outp = (z == 0) ? o0 : o1;
#pragma unroll
        for (int mi = 0; mi < 4; ++mi)
#pragma unroll
            for (int ni = 0; ni < 4; ++ni)
#pragma unroll
                for (int r = 0; r < 4; ++r) {
                    int m = bm * 128 + wm + mi * 16 + quad * 4 + r;
                    int n = bn * 128 + wn + ni * 16 + l15;
                    outp[(size_t)m * H_ + n] = f2bf(acc[mi][ni][r] + bvv[ni]);
                }
    } else {
        // V^T via LDS transpose: half = n-range 64 (waves 0,1 own half 0).
        // sT aliases sA/sB -> must drain K-loop LDS reads first.
        __syncthreads();
        const int halfw = w >> 1;
        const int bb = bm >> 4;                 // batch of this row-block
        const int s0 = (bm * 128) & 2047;       // seq offset of this row-block
        for (int half = 0; half < 2; ++half) {
            if (half) __syncthreads();          // half-0 reads done before overwrite
            if (halfw == half) {
#pragma unroll
                for (int mi = 0; mi < 4; ++mi)
#pragma unroll
                    for (int ni = 0; ni < 4; ++ni)
#pragma unroll
                        for (int r = 0; r < 4; ++r) {
                            int nl = ni * 16 + l15;
                            int m  = wm + mi * 16 + quad * 4 + r;
                            sT[nl * 136 + m] = f2bf(acc[mi][ni][r] + bvv[ni]);
                        }
            }
            __syncthreads();
            {   // coalesced store: thread t -> row n=t/4, 32 s-elems
                int nl = t >> 2, mc = (t & 3) * 32;
                int ng = bn * 128 + half * 64 + nl;
                int hh = ng >> 6, d = ng & 63;
                size_t base = ((size_t)((bb * NH_ + hh) * HD_ + d)) * S_ + s0 + mc;
#pragma unroll
                for (int i = 0; i < 4; ++i)
                    *(u16x8*)(o2 + base + i * 8) = *(const u16x8*)&sT[nl * 136 + mc + i * 8];
            }
        }
    }
}

// ---------------------------------------------------------------------------
// Flash attention R12: UNFUSED q-tiles. 2048 blocks; block handles ONE
// q-tile qt with kt = 0..qt. R9's PROVEN staging: per iter {store regs ->
// buf[cur]; prefetch kt+1 -> regs; barrier; compute buf[cur]}. Swapped QK^T
// (S^T layout), cvt_pk P-pack, b64 P-writes, scalar row-sums.
// Decode: bh=(lid&7)+8*(lid>>8) -> 8 bh per XCD under both dispatch models
// (K/V L2-resident); qt=31-((lid>>3)&31) -> longest blocks dispatch first.
// LDS 40960 B.
// ---------------------------------------------------------------------------
__global__ __launch_bounds__(256, 3) void attn(
    const unsigned short* __restrict__ qg, const unsigned short* __restrict__ kg,
    const unsigned short* __restrict__ vtg, const float* __restrict__ mcg,
    float* __restrict__ outg) {
    __shared__ unsigned short k_s[2][64 * 64];
    __shared__ unsigned short v_s[2][64 * 64];
    __shared__ unsigned short p_s[4][16 * 64];

    const int t = threadIdx.x;
    const int w = t >> 6, lane = t & 63, quad = lane >> 4, l15 = lane & 15;
    const int lid = blockIdx.x;
    const int bh = (lid & 7) + ((lid >> 8) << 3);   // XCD-grouped head-batch
    const int qt = 31 - ((lid >> 3) & 31);          // LPT: long blocks first
    const int b = bh >> 4, h = bh & 15;

    const int rs_ = t >> 2;             // staging row 0..63
    const int cs_ = (t & 3) * 16;       // staging col
    const int sc0 = rs_ * 64 + SWZ(rs_, cs_);      // swizzled staging offsets
    const int sc1 = rs_ * 64 + SWZ(rs_, cs_ + 8);

    const unsigned short* kbase = kg + ((size_t)b * S_ + rs_) * H_ + h * HD_ + cs_;
    const unsigned short* vbase = vtg + ((size_t)bh * HD_ + rs_) * S_ + cs_;
    const float* mrow = mcg + b * S_ + quad * 4;   // + kt*64 + jt*16 (float4)

    // Q A-frags, direct global (once per block)
    bf16x8 aq[2];
    {
        const unsigned short* qp =
            qg + ((size_t)(b * S_ + qt * 64 + w * 16 + l15)) * H_ + h * HD_ + quad * 8;
        aq[0] = *(const bf16x8*)qp;
        aq[1] = *(const bf16x8*)(qp + 32);
    }

    // prefetch tile 0 into regs
    u16x8 pk0 = *(const u16x8*)kbase, pk1 = *(const u16x8*)(kbase + 8);
    u16x8 pv0 = *(const u16x8*)vbase, pv1 = *(const u16x8*)(vbase + 8);

    f32x4 o[4];
    float ls = 0.f;                    // scalar row-sum partial (row q = l15)
#pragma unroll
    for (int dt = 0; dt < 4; ++dt) o[dt] = f32x4{0.f, 0.f, 0.f, 0.f};

    const int ig0  = qt * 64 + w * 16 + quad * 4;   // output row base (C layout)
    const int qcol = qt * 64 + w * 16 + l15;        // causal col (swapped layout)
    const int pwr0 = l15 * 64;                      // P base (swizzled below)

    for (int kt = 0; kt <= qt; ++kt) {
        const int cur = kt & 1;
        // store regs (tile kt) -> buf[cur], swizzled  (R9 proven staging)
        *(u16x8*)&k_s[cur][sc0] = pk0;
        *(u16x8*)&k_s[cur][sc1] = pk1;
        *(u16x8*)&v_s[cur][sc0] = pv0;
        *(u16x8*)&v_s[cur][sc1] = pv1;
        // prefetch tile kt+1 -> regs (consumed at next iter's store)
        if (kt < qt) {
            const unsigned short* kp = kbase + (size_t)(kt + 1) * 64 * H_;
            pk0 = *(const u16x8*)kp; pk1 = *(const u16x8*)(kp + 8);
            const unsigned short* vp = vbase + (kt + 1) * 64;
            pv0 = *(const u16x8*)vp; pv1 = *(const u16x8*)(vp + 8);
        }
        __syncthreads();   // buf[cur] visible to all; prev iter compute done

        // mask (prescaled by CEXP): mcv[jt][r] at s = kt*64 + jt*16 + quad*4 + r
        float4 mcv[4];
#pragma unroll
        for (int jt = 0; jt < 4; ++jt)
            mcv[jt] = *(const float4*)(mrow + kt * 64 + jt * 16);

        // ===== QK^T (swapped: D = K·Q^T = S^T; col=q, row=s) =====
        f32x4 sc[4];
#pragma unroll
        for (int jt = 0; jt < 4; ++jt) sc[jt] = f32x4{0.f, 0.f, 0.f, 0.f};
        __builtin_amdgcn_s_setprio(1);
#pragma unroll
        for (int c = 0; c < 2; ++c)
#pragma unroll
            for (int jt = 0; jt < 4; ++jt) {
                int row = jt * 16 + l15;
                bf16x8 bk = *(const bf16x8*)&k_s[cur][row * 64 + SWZ(row, c * 32 + quad * 8)];
                sc[jt] = __builtin_amdgcn_mfma_f32_16x16x32_bf16(bk, aq[c], sc[jt], 0, 0, 0);
            }
        __builtin_amdgcn_s_setprio(0);

        // ===== softmax -> p_s (P contiguous in s per lane) =====
        const bool diag = (kt == qt);
#pragma unroll
        for (int jt = 0; jt < 4; ++jt) {
            const int sb0 = kt * 64 + jt * 16 + quad * 4;
            float p0 = __builtin_amdgcn_exp2f(__builtin_fmaf(sc[jt][0], CEXP, mcv[jt].x));
            float p1 = __builtin_amdgcn_exp2f(__builtin_fmaf(sc[jt][1], CEXP, mcv[jt].y));
            float p2 = __builtin_amdgcn_exp2f(__builtin_fmaf(sc[jt][2], CEXP, mcv[jt].z));
            float p3 = __builtin_amdgcn_exp2f(__builtin_fmaf(sc[jt][3], CEXP, mcv[jt].w));
            if (diag) {
                if (sb0 + 0 > qcol) p0 = 0.f;
                if (sb0 + 1 > qcol) p1 = 0.f;
                if (sb0 + 2 > qcol) p2 = 0.f;
                if (sb0 + 3 > qcol) p3 = 0.f;
            }
            ls += (p0 + p1) + (p2 + p3);
            u32x2 pw;
            pw[0] = cvt_pk_bf16(p0, p1);
            pw[1] = cvt_pk_bf16(p2, p3);
            *(u32x2*)&p_s[w][pwr0 + SWZ(l15, jt * 16 + quad * 4)] = pw;
        }

        // ===== PV =====
        __builtin_amdgcn_s_setprio(1);
#pragma unroll
        for (int c = 0; c < 2; ++c) {
            bf16x8 ap = *(const bf16x8*)&p_s[w][l15 * 64 + SWZ(l15, c * 32 + quad * 8)];
#pragma unroll
            for (int dt = 0; dt < 4; ++dt) {
                int row = dt * 16 + l15;
                bf16x8 bv = *(const bf16x8*)&v_s[cur][row * 64 + SWZ(row, c * 32 + quad * 8)];
                o[dt] = __builtin_amdgcn_mfma_f32_16x16x32_bf16(ap, bv, o[dt], 0, 0, 0);
            }
        }
        __builtin_amdgcn_s_setprio(0);
    }

    // ---- epilogue: complete row sums (rows live at q = l15), redistribute
    // to the O-accumulator rows (quad*4+r), normalize, store fp32 ----
    float sa = ls;
    sa += __shfl_xor(sa, 16); sa += __shfl_xor(sa, 32);
    float ra[4];
#pragma unroll
    for (int r = 0; r < 4; ++r) {
        int src = (quad << 4) | (quad * 4 + r);   // lane with l15 = quad*4+r
        ra[r] = 1.0f / __shfl(sa, src);
    }
#pragma unroll
    for (int dt = 0; dt < 4; ++dt)
#pragma unroll
        for (int r = 0; r < 4; ++r) {
            int col = h * HD_ + dt * 16 + l15;
            outg[(size_t)(b * S_ + ig0 + r) * H_ + col] = o[dt][r] * ra[r];
        }
}

// ---------------------------------------------------------------------------
extern "C" void kernel_launch(void* const* d_in, const int* in_sizes, int n_in,
                              void* d_out, int out_size, void* d_ws, size_t ws_size,
                              hipStream_t stream) {
    const float* hs   = (const float*)d_in[0];
    const float* mask = (const float*)d_in[1];
    const float* Wq   = (const float*)d_in[2];
    const float* bq   = (const float*)d_in[3];
    const float* Wk   = (const float*)d_in[4];
    const float* bk   = (const float*)d_in[5];
    const float* Wv   = (const float*)d_in[6];
    const float* bv   = (const float*)d_in[7];
    float* out = (float*)d_out;

    // ws carve (bf16 elems): hsb 8M | wq,wk,wv 1M | q 8M | k 8M | vT 8M | mc 8K f32
    unsigned short* hsb = (unsigned short*)d_ws;
    unsigned short* wqb = hsb + (size_t)M_ * H_;
    unsigned short* wkb = wqb + (size_t)H_ * H_;
    unsigned short* wvb = wkb + (size_t)H_ * H_;
    unsigned short* qb  = wvb + (size_t)H_ * H_;
    unsigned short* kb  = qb  + (size_t)M_ * H_;
    unsigned short* vtb = kb  + (size_t)M_ * H_;
    float*          mcw = (float*)(vtb + (size_t)M_ * H_);

    cast_bf16<<<dim3(5636), 256, 0, stream>>>(
        hs, Wq, Wk, Wv, mask, hsb, wqb, wkb, wvb, mcw);

    qkv_gemm<<<dim3(M_ / 128, H_ / 128, 3), 256, 0, stream>>>(
        hsb, wqb, wkb, wvb, bq, bk, bv, qb, kb, vtb);

    attn<<<dim3(2048), 256, 0, stream>>>(qb, kb, vtb, mcw, out);
}